// Round 12
// baseline (108.067 us; speedup 1.0000x reference)
//
#include <hip/hip_runtime.h>
#include <hip/hip_bf16.h>

typedef short short8 __attribute__((ext_vector_type(8)));
typedef float f32x4 __attribute__((ext_vector_type(4)));
typedef float f32x16 __attribute__((ext_vector_type(16)));
typedef __hip_bfloat16 bf16;

// Problem constants: B=2, S=2048, D=1024, H=16, HD=64, SCALE=1/8

__device__ __forceinline__ void glds16(const void* g, void* l) {
  __builtin_amdgcn_global_load_lds((const __attribute__((address_space(1))) unsigned int*)g,
                                   (__attribute__((address_space(3))) unsigned int*)l, 16, 0, 0);
}

__device__ __forceinline__ uint pk2(float a, float b) {
  union { bf16 h2[2]; uint u; } pk;
  pk.h2[0] = __float2bfloat16(a);
  pk.h2[1] = __float2bfloat16(b);
  return pk.u;
}

// ------------------------------------------------- prep: cvt src + transpose w
__global__ __launch_bounds__(256) void prep_kernel(const float4* __restrict__ in,
                                                   bf16* __restrict__ src_bf,
                                                   const float* __restrict__ w,
                                                   bf16* __restrict__ wt) {
  __shared__ float tile[32][33];
  const int bid = blockIdx.x;
  if (bid < 4096) {
    int i = bid * 256 + threadIdx.x;
    float4 v = in[i];
    union { bf16 h[4]; uint2 u; } pk;
    pk.h[0] = __float2bfloat16(v.x);
    pk.h[1] = __float2bfloat16(v.y);
    pk.h[2] = __float2bfloat16(v.z);
    pk.h[3] = __float2bfloat16(v.w);
    *(uint2*)(src_bf + (size_t)i * 4) = pk.u;
  } else {
    int id = bid - 4096;  // 0..3071
    int x0 = (id % 96) * 32;
    int y0 = (id / 96) * 32;
    int tx = threadIdx.x & 31, ty = threadIdx.x >> 5;
#pragma unroll
    for (int i = 0; i < 4; i++) {
      int y = ty + i * 8;
      tile[y][tx] = w[(size_t)(y0 + y) * 3072 + x0 + tx];
    }
    __syncthreads();
#pragma unroll
    for (int i = 0; i < 4; i++) {
      int y = ty + i * 8;
      wt[(size_t)(x0 + y) * 1024 + y0 + tx] = __float2bfloat16(tile[tx][y]);
    }
  }
}

// ------------------------------------------------------------ QKV GEMM v2 (verified)
// Q output pre-scaled by SCALE*log2(e).
__global__ __launch_bounds__(256) void qkv_gemm_kernel(
    const bf16* __restrict__ A, const bf16* __restrict__ Bt,
    const float* __restrict__ bias,
    bf16* __restrict__ q_ws, bf16* __restrict__ k_ws, bf16* __restrict__ vt_ws) {
  __shared__ alignas(16) char AB[32768];  // As [0,16K), Bs [16K,32K)
  const int tid = threadIdx.x;
  const int lane = tid & 63, wid = tid >> 6;
  const int lr = lane & 15, lg = lane >> 4;
  const int wm = wid >> 1, wn = wid & 1;
  const int m0 = blockIdx.x * 128, n0 = blockIdx.y * 128;

  const f32x4 z4 = {0.f, 0.f, 0.f, 0.f};
  f32x4 acc[4][4];
#pragma unroll
  for (int m = 0; m < 4; m++)
#pragma unroll
    for (int n = 0; n < 4; n++) acc[m][n] = z4;

  const int srow = lane >> 3;
  const int sseg = (lane & 7) ^ srow;
  const char* Ag = (const char*)A + (size_t)(m0 + wid * 32 + srow) * 2048 + sseg * 16;
  const char* Bg = (const char*)Bt + (size_t)(n0 + wid * 32 + srow) * 2048 + sseg * 16;
  char* Al = AB + wid * 4096;
  char* Bl = AB + 16384 + wid * 4096;
  const int xora = (lr & 7) << 4;

  for (int kt = 0; kt < 16; kt++) {
    __syncthreads();
#pragma unroll
    for (int c = 0; c < 4; c++) {
      glds16(Ag + (size_t)kt * 128 + c * 16384, Al + c * 1024);
      glds16(Bg + (size_t)kt * 128 + c * 16384, Bl + c * 1024);
    }
    asm volatile("s_waitcnt vmcnt(0)" ::: "memory");
    __syncthreads();
#pragma unroll
    for (int g = 0; g < 2; g++) {
      short8 af[4], bfr[4];
#pragma unroll
      for (int m = 0; m < 4; m++)
        af[m] = *(const short8*)(AB + (wm * 64 + m * 16 + lr) * 128 +
                                 ((g * 64 + lg * 16) ^ xora));
#pragma unroll
      for (int n = 0; n < 4; n++)
        bfr[n] = *(const short8*)(AB + 16384 + (wn * 64 + n * 16 + lr) * 128 +
                                  ((g * 64 + lg * 16) ^ xora));
#pragma unroll
      for (int m = 0; m < 4; m++)
#pragma unroll
        for (int n = 0; n < 4; n++)
          acc[m][n] = __builtin_amdgcn_mfma_f32_16x16x32_bf16(af[m], bfr[n], acc[m][n], 0, 0, 0);
    }
  }

  const int which = n0 >> 10;
  const float scl = (which == 0) ? 0.18033688f : 1.0f;  // SCALE*log2(e) folded into Q
#pragma unroll
  for (int m = 0; m < 4; m++) {
    int row = m0 + wm * 64 + m * 16 + lg * 4;
    int b = row >> 11;
    int ss0 = row & 2047;
#pragma unroll
    for (int n = 0; n < 4; n++) {
      int col = n0 + wn * 64 + n * 16 + lr;
      int d = col & 1023;
      int h = d >> 6, hd = d & 63;
      size_t bh = (size_t)(b * 16 + h);
      float bv = bias[col];
      if (which == 2) {
        union { bf16 h4[4]; uint2 u; } pk;
#pragma unroll
        for (int r = 0; r < 4; r++) pk.h4[r] = __float2bfloat16(acc[m][n][r] + bv);
        *(uint2*)&vt_ws[(bh * 64 + hd) * 2048 + ss0] = pk.u;
      } else {
        bf16* dst = (which == 0) ? q_ws : k_ws;
#pragma unroll
        for (int r = 0; r < 4; r++)
          dst[(bh * 2048 + (ss0 + r)) * 64 + hd] = __float2bfloat16((acc[m][n][r] + bv) * scl);
      }
    }
  }
}

// ------------------------------------------------------------ attention v12
// R11 body (verified: pi-perm K, no-max softmax, deferred sum) re-parametrized
// to 512 blocks x 4 waves (128 q/block): 2 co-resident blocks/CU so the two
// blocks' barrier drains interleave (block-level decoupling of the lockstep).
#define KPERM(p) (((p) & ~31) | ((p) & 3) | ((((p) >> 2) & 1) << 3) | \
                  ((((p) >> 3) & 1) << 4) | ((((p) >> 4) & 1) << 2))

__global__ __launch_bounds__(256) void attn8_kernel(
    const bf16* __restrict__ q_ws, const bf16* __restrict__ k_ws,
    const bf16* __restrict__ vt_ws, float* __restrict__ out) {
  // [0,32K): K bufs [2][128][64] bf16 (row&7 xor-swz, pi-permuted rows);
  // [32K,64K): V^T bufs [2][64][128] bf16 (256B rows, chunk ^ (d&15) swz)
  __shared__ alignas(16) char smem[65536];
  const int tid = threadIdx.x;
  const int lane = tid & 63, wid = tid >> 6;   // wid 0..3
  const int lq = lane & 31, hi = lane >> 5;
  const int hi16 = hi * 16;
  const int xorv = (lq & 7) << 4;

  const int f = blockIdx.x;                    // 512 blocks
  const int bh = (f & 7) * 4 + ((f >> 3) & 3);
  const int qb = f >> 5;                       // 0..15
  const int b = bh >> 4, h = bh & 15;
  const int q0 = qb * 128 + wid * 32;

  short8 qf[4];
  {
    const bf16* qrow = q_ws + ((size_t)bh * 2048 + q0 + lq) * 64;
#pragma unroll
    for (int s = 0; s < 4; s++) qf[s] = *(const short8*)(qrow + s * 16 + hi * 8);
  }

  // staging: wave w stages K rows w*32 + c*8 + l8 (pi-permuted source),
  // V d-rows w*16 + c*4 + l16 (chunk-swizzled source), c = 0..3.
  const int l8 = lane >> 3;
  const int segk = (lane & 7) ^ l8;
  const int l16 = lane >> 4;
  const char* kgl[4];
  const char* vgl[4];
#pragma unroll
  for (int c = 0; c < 4; c++) {
    const int p = wid * 32 + c * 8 + l8;
    kgl[c] = (const char*)k_ws + (size_t)bh * 262144 + (size_t)KPERM(p) * 128 + segk * 16;
    const int dv = wid * 16 + c * 4 + l16;
    vgl[c] = (const char*)vt_ws + (size_t)bh * 262144 + (size_t)dv * 4096 +
             (((lane & 15) ^ (dv & 15)) << 4);
  }

  f32x16 o0a, o0b, o1a, o1b, lacc;
#pragma unroll
  for (int r = 0; r < 16; r++) {
    o0a[r] = 0.f; o0b[r] = 0.f; o1a[r] = 0.f; o1b[r] = 0.f; lacc[r] = 0.f;
  }

#pragma unroll
  for (int c = 0; c < 4; c++) {
    glds16(kgl[c], smem + wid * 4096 + c * 1024);
    glds16(vgl[c], smem + 32768 + wid * 4096 + c * 1024);
  }
  asm volatile("s_waitcnt vmcnt(0)" ::: "memory");
  __builtin_amdgcn_s_barrier();

  for (int kt = 0; kt < 16; ++kt) {
    const int kb_off = (kt & 1) * 16384;
    const int vb_off = 32768 + (kt & 1) * 16384;
    if (kt + 1 < 16) {
      const int nb = ((kt + 1) & 1) * 16384;
#pragma unroll
      for (int c = 0; c < 4; c++) {
        glds16(kgl[c] + (size_t)(kt + 1) * 16384, smem + nb + wid * 4096 + c * 1024);
        glds16(vgl[c] + (size_t)(kt + 1) * 256, smem + 32768 + nb + wid * 4096 + c * 1024);
      }
    }

    // ---- S^T = K * Q^T : 4 independent 32-key groups ----
    f32x16 s0, s1, s2, s3;
#pragma unroll
    for (int r = 0; r < 16; r++) { s0[r] = 0.f; s1[r] = 0.f; s2[r] = 0.f; s3[r] = 0.f; }
#pragma unroll
    for (int st = 0; st < 4; st++) {
      const int doff = (st * 32 + hi16) ^ xorv;
      short8 ka = *(const short8*)(smem + kb_off + lq * 128 + doff);
      short8 kb = *(const short8*)(smem + kb_off + (lq + 32) * 128 + doff);
      short8 kc = *(const short8*)(smem + kb_off + (lq + 64) * 128 + doff);
      short8 kd = *(const short8*)(smem + kb_off + (lq + 96) * 128 + doff);
      __builtin_amdgcn_s_setprio(1);
      s0 = __builtin_amdgcn_mfma_f32_32x32x16_bf16(ka, qf[st], s0, 0, 0, 0);
      s1 = __builtin_amdgcn_mfma_f32_32x32x16_bf16(kb, qf[st], s1, 0, 0, 0);
      s2 = __builtin_amdgcn_mfma_f32_32x32x16_bf16(kc, qf[st], s2, 0, 0, 0);
      s3 = __builtin_amdgcn_mfma_f32_32x32x16_bf16(kd, qf[st], s3, 0, 0, 0);
      __builtin_amdgcn_s_setprio(0);
    }

    // ---- no-max softmax (scale pre-folded into Q); deferred row-sum ----
#pragma unroll
    for (int r = 0; r < 16; r++) {
      s0[r] = __builtin_amdgcn_exp2f(s0[r]);
      s1[r] = __builtin_amdgcn_exp2f(s1[r]);
      s2[r] = __builtin_amdgcn_exp2f(s2[r]);
      s3[r] = __builtin_amdgcn_exp2f(s3[r]);
    }
#pragma unroll
    for (int r = 0; r < 16; r++)
      lacc[r] += (s0[r] + s1[r]) + (s2[r] + s3[r]);

    // ---- O^T += V^T * P^T ; pi-perm makes P-frags pure packing ----
#define PV_KB(S, KB, OA, OB)                                                     \
  {                                                                              \
    union { uint u[4]; short8 s8; } ua, ub;                                      \
    ua.u[0] = pk2(S[0], S[1]);   ua.u[1] = pk2(S[2], S[3]);                      \
    ua.u[2] = pk2(S[8], S[9]);   ua.u[3] = pk2(S[10], S[11]);                    \
    ub.u[0] = pk2(S[4], S[5]);   ub.u[1] = pk2(S[6], S[7]);                      \
    ub.u[2] = pk2(S[12], S[13]); ub.u[3] = pk2(S[14], S[15]);                    \
    const int c0 = (((KB) * 4 + hi) ^ (lq & 15)) << 4;                           \
    const int c1 = (((KB) * 4 + 2 + hi) ^ (lq & 15)) << 4;                       \
    short8 va0 = *(const short8*)(smem + vb_off + lq * 256 + c0);                \
    short8 va1 = *(const short8*)(smem + vb_off + (lq + 32) * 256 + c0);         \
    short8 vb0 = *(const short8*)(smem + vb_off + lq * 256 + c1);                \
    short8 vb1 = *(const short8*)(smem + vb_off + (lq + 32) * 256 + c1);         \
    __builtin_amdgcn_s_setprio(1);                                               \
    OA = __builtin_amdgcn_mfma_f32_32x32x16_bf16(va0, ua.s8, OA, 0, 0, 0);       \
    OB = __builtin_amdgcn_mfma_f32_32x32x16_bf16(va1, ua.s8, OB, 0, 0, 0);       \
    OA = __builtin_amdgcn_mfma_f32_32x32x16_bf16(vb0, ub.s8, OA, 0, 0, 0);       \
    OB = __builtin_amdgcn_mfma_f32_32x32x16_bf16(vb1, ub.s8, OB, 0, 0, 0);       \
    __builtin_amdgcn_s_setprio(0);                                               \
  }
    PV_KB(s0, 0, o0a, o1a)
    PV_KB(s1, 1, o0b, o1b)
    PV_KB(s2, 2, o0a, o1a)
    PV_KB(s3, 3, o0b, o1b)
#undef PV_KB

    if (kt < 15) {
      asm volatile("s_waitcnt vmcnt(0)" ::: "memory");
      __builtin_amdgcn_s_barrier();
    }
  }
  __syncthreads();

  // ---- final row-sum (one tree), 1/l, transpose via rotated LDS ----
  float l;
  {
    float sm[8];
#pragma unroll
    for (int i = 0; i < 8; i++) sm[i] = lacc[i] + lacc[i + 8];
#pragma unroll
    for (int i = 0; i < 4; i++) sm[i] += sm[i + 4];
    l = (sm[0] + sm[1]) + (sm[2] + sm[3]);
    l += __shfl_xor(l, 32);
  }
  f32x16 o0, o1;
#pragma unroll
  for (int r = 0; r < 16; r++) { o0[r] = o0a[r] + o0b[r]; o1[r] = o1a[r] + o1b[r]; }
  float* ep = (float*)(smem) + wid * 1024;
  const float invl = 1.f / l;
  const int eq = lane >> 1, eds = lane & 1;
  float* obase = out + ((size_t)b * 2048 + qb * 128 + wid * 32 + eq) * 1024 +
                 h * 64 + eds * 16;
#pragma unroll
  for (int db = 0; db < 2; db++) {
#pragma unroll
    for (int r = 0; r < 16; r++) {
      int d = (r & 3) + 8 * (r >> 2) + 4 * hi;
      float v = (db ? o1[r] : o0[r]) * invl;
      ep[lq * 32 + ((d + lq) & 31)] = v;
    }
#pragma unroll
    for (int c = 0; c < 4; c++) {
      float4 t;
      t.x = ep[eq * 32 + ((eds * 16 + 4 * c + 0 + eq) & 31)];
      t.y = ep[eq * 32 + ((eds * 16 + 4 * c + 1 + eq) & 31)];
      t.z = ep[eq * 32 + ((eds * 16 + 4 * c + 2 + eq) & 31)];
      t.w = ep[eq * 32 + ((eds * 16 + 4 * c + 3 + eq) & 31)];
      *(float4*)(obase + db * 32 + 4 * c) = t;
    }
  }
}

// ---------------------------------------------------------------- launch
extern "C" void kernel_launch(void* const* d_in, const int* in_sizes, int n_in,
                              void* d_out, int out_size, void* d_ws, size_t ws_size,
                              hipStream_t stream) {
  (void)in_sizes; (void)n_in; (void)out_size; (void)ws_size;
  const float* src  = (const float*)d_in[0];
  const float* w    = (const float*)d_in[1];
  const float* bias = (const float*)d_in[2];
  float* out = (float*)d_out;

  char* ws = (char*)d_ws;
  bf16* src_bf = (bf16*)ws;                             // 8,388,608 B
  bf16* wt_bf  = (bf16*)(ws + 8388608);                 // 6,291,456 B
  bf16* q_ws   = (bf16*)(ws + 8388608 + 6291456);       // 32*2048*64 each
  bf16* k_ws   = q_ws + 4194304;
  bf16* vt_ws  = k_ws + 4194304;

  prep_kernel<<<7168, 256, 0, stream>>>((const float4*)src, src_bf, w, wt_bf);
  qkv_gemm_kernel<<<dim3(32, 24), 256, 0, stream>>>(src_bf, wt_bf, bias, q_ws, k_ws, vt_ws);
  attn8_kernel<<<512, 256, 0, stream>>>(q_ws, k_ws, vt_ws, out);
}

// Round 13
// 89.565 us; speedup vs baseline: 1.2066x; 1.2066x over previous
//
#include <hip/hip_runtime.h>
#include <hip/hip_bf16.h>

typedef short short8 __attribute__((ext_vector_type(8)));
typedef float f32x4 __attribute__((ext_vector_type(4)));
typedef float f32x16 __attribute__((ext_vector_type(16)));
typedef __hip_bfloat16 bf16;

// Problem constants: B=2, S=2048, D=1024, H=16, HD=64, SCALE=1/8

__device__ __forceinline__ void glds16(const void* g, void* l) {
  __builtin_amdgcn_global_load_lds((const __attribute__((address_space(1))) unsigned int*)g,
                                   (__attribute__((address_space(3))) unsigned int*)l, 16, 0, 0);
}

__device__ __forceinline__ uint pk2(float a, float b) {
  union { bf16 h2[2]; uint u; } pk;
  pk.h2[0] = __float2bfloat16(a);
  pk.h2[1] = __float2bfloat16(b);
  return pk.u;
}

// ------------------------------------------------- prep: cvt src + transpose w
// transpose now uses 64-row y-tiles + packed uint stores (128B store rows).
__global__ __launch_bounds__(256) void prep_kernel(const float4* __restrict__ in,
                                                   bf16* __restrict__ src_bf,
                                                   const float* __restrict__ w,
                                                   bf16* __restrict__ wt) {
  __shared__ float tile[64][33];
  const int bid = blockIdx.x;
  if (bid < 4096) {
    int i = bid * 256 + threadIdx.x;
    float4 v = in[i];
    union { bf16 h[4]; uint2 u; } pk;
    pk.h[0] = __float2bfloat16(v.x);
    pk.h[1] = __float2bfloat16(v.y);
    pk.h[2] = __float2bfloat16(v.z);
    pk.h[3] = __float2bfloat16(v.w);
    *(uint2*)(src_bf + (size_t)i * 4) = pk.u;
  } else {
    int id = bid - 4096;                 // 0..1535
    int x0 = (id % 96) * 32;             // w col
    int y0 = (id / 96) * 64;             // w row
    int tx = threadIdx.x & 31, ty = threadIdx.x >> 5;
#pragma unroll
    for (int i = 0; i < 8; i++) {
      int y = ty + i * 8;
      tile[y][tx] = w[(size_t)(y0 + y) * 3072 + x0 + tx];
    }
    __syncthreads();
#pragma unroll
    for (int j = 0; j < 4; j++) {
      int r = ty + j * 8;
      uint u = pk2(tile[2 * tx][r], tile[2 * tx + 1][r]);
      *(uint*)&wt[(size_t)(x0 + r) * 1024 + y0 + 2 * tx] = u;
    }
  }
}

// ------------------------------------------------------------ QKV GEMM v2 (verified)
// + XCD-chunked block remap: each XCD owns a 4x24 patch of the 32x24 tile grid.
// Q output pre-scaled by SCALE*log2(e).
__global__ __launch_bounds__(256) void qkv_gemm_kernel(
    const bf16* __restrict__ A, const bf16* __restrict__ Bt,
    const float* __restrict__ bias,
    bf16* __restrict__ q_ws, bf16* __restrict__ k_ws, bf16* __restrict__ vt_ws) {
  __shared__ alignas(16) char AB[32768];  // As [0,16K), Bs [16K,32K)
  const int tid = threadIdx.x;
  const int lane = tid & 63, wid = tid >> 6;
  const int lr = lane & 15, lg = lane >> 4;
  const int wm = wid >> 1, wn = wid & 1;
  const int lin = blockIdx.y * 32 + blockIdx.x;
  const int xcd = lin & 7, idx = lin >> 3;       // 768 % 8 == 0: bijective
  const int bx = xcd * 4 + (idx & 3);
  const int by = idx >> 2;
  const int m0 = bx * 128, n0 = by * 128;

  const f32x4 z4 = {0.f, 0.f, 0.f, 0.f};
  f32x4 acc[4][4];
#pragma unroll
  for (int m = 0; m < 4; m++)
#pragma unroll
    for (int n = 0; n < 4; n++) acc[m][n] = z4;

  const int srow = lane >> 3;
  const int sseg = (lane & 7) ^ srow;
  const char* Ag = (const char*)A + (size_t)(m0 + wid * 32 + srow) * 2048 + sseg * 16;
  const char* Bg = (const char*)Bt + (size_t)(n0 + wid * 32 + srow) * 2048 + sseg * 16;
  char* Al = AB + wid * 4096;
  char* Bl = AB + 16384 + wid * 4096;
  const int xora = (lr & 7) << 4;

  for (int kt = 0; kt < 16; kt++) {
    __syncthreads();
#pragma unroll
    for (int c = 0; c < 4; c++) {
      glds16(Ag + (size_t)kt * 128 + c * 16384, Al + c * 1024);
      glds16(Bg + (size_t)kt * 128 + c * 16384, Bl + c * 1024);
    }
    asm volatile("s_waitcnt vmcnt(0)" ::: "memory");
    __syncthreads();
#pragma unroll
    for (int g = 0; g < 2; g++) {
      short8 af[4], bfr[4];
#pragma unroll
      for (int m = 0; m < 4; m++)
        af[m] = *(const short8*)(AB + (wm * 64 + m * 16 + lr) * 128 +
                                 ((g * 64 + lg * 16) ^ xora));
#pragma unroll
      for (int n = 0; n < 4; n++)
        bfr[n] = *(const short8*)(AB + 16384 + (wn * 64 + n * 16 + lr) * 128 +
                                  ((g * 64 + lg * 16) ^ xora));
#pragma unroll
      for (int m = 0; m < 4; m++)
#pragma unroll
        for (int n = 0; n < 4; n++)
          acc[m][n] = __builtin_amdgcn_mfma_f32_16x16x32_bf16(af[m], bfr[n], acc[m][n], 0, 0, 0);
    }
  }

  const int which = n0 >> 10;
  const float scl = (which == 0) ? 0.18033688f : 1.0f;  // SCALE*log2(e) folded into Q
#pragma unroll
  for (int m = 0; m < 4; m++) {
    int row = m0 + wm * 64 + m * 16 + lg * 4;
    int b = row >> 11;
    int ss0 = row & 2047;
#pragma unroll
    for (int n = 0; n < 4; n++) {
      int col = n0 + wn * 64 + n * 16 + lr;
      int d = col & 1023;
      int h = d >> 6, hd = d & 63;
      size_t bh = (size_t)(b * 16 + h);
      float bv = bias[col];
      if (which == 2) {
        union { bf16 h4[4]; uint2 u; } pk;
#pragma unroll
        for (int r = 0; r < 4; r++) pk.h4[r] = __float2bfloat16(acc[m][n][r] + bv);
        *(uint2*)&vt_ws[(bh * 64 + hd) * 2048 + ss0] = pk.u;
      } else {
        bf16* dst = (which == 0) ? q_ws : k_ws;
#pragma unroll
        for (int r = 0; r < 4; r++)
          dst[(bh * 2048 + (ss0 + r)) * 64 + hd] = __float2bfloat16((acc[m][n][r] + bv) * scl);
      }
    }
  }
}

// ------------------------------------------------------------ attention v13
// R11 body (verified: pi-perm K, no-max softmax, deferred sum, 8 waves x 32 q)
// + 4-buffer pair-barrier pipeline: stage tile t+2 at iter t; {vmcnt(0);barrier}
// only after odd iters -> barrier convergence points halved (15 -> 8).
// Ledger: stage(t+2) overwrites buf[(t-2)&3], whose reads (iter t-2) are
// separated from the issue by the pair barrier; reads of tile t are covered by
// the vmcnt(0)+barrier between iter t-2 (its issue) and iter t.
#define KPERM(p) (((p) & ~31) | ((p) & 3) | ((((p) >> 2) & 1) << 3) | \
                  ((((p) >> 3) & 1) << 4) | ((((p) >> 4) & 1) << 2))

__global__ __launch_bounds__(512) void attn9_kernel(
    const bf16* __restrict__ q_ws, const bf16* __restrict__ k_ws,
    const bf16* __restrict__ vt_ws, float* __restrict__ out) {
  // [0,64K): K bufs [4][128][64] bf16 (row&7 xor-swz, pi-permuted rows);
  // [64K,128K): V^T bufs [4][64][128] bf16 (256B rows, chunk ^ (d&15) swz)
  __shared__ alignas(16) char smem[131072];
  const int tid = threadIdx.x;
  const int lane = tid & 63, wid = tid >> 6;
  const int lq = lane & 31, hi = lane >> 5;
  const int hi16 = hi * 16;
  const int xorv = (lq & 7) << 4;

  const int f = blockIdx.x;
  const int bh = (f & 7) * 4 + ((f >> 3) & 3);
  const int qb = f >> 5;
  const int b = bh >> 4, h = bh & 15;
  const int q0 = qb * 256 + wid * 32;

  short8 qf[4];
  {
    const bf16* qrow = q_ws + ((size_t)bh * 2048 + q0 + lq) * 64;
#pragma unroll
    for (int s = 0; s < 4; s++) qf[s] = *(const short8*)(qrow + s * 16 + hi * 8);
  }

  const int l8 = lane >> 3;
  const int segk = (lane & 7) ^ l8;
  const int p0 = wid * 16 + l8;
  const int p1 = p0 + 8;
  const char* kgl0 = (const char*)k_ws + (size_t)bh * 262144 +
                     (size_t)KPERM(p0) * 128 + segk * 16;
  const char* kgl1 = (const char*)k_ws + (size_t)bh * 262144 +
                     (size_t)KPERM(p1) * 128 + segk * 16;
  const int l16 = lane >> 4;
  const int d0v = (wid * 2 + 0) * 4 + l16;
  const int d1v = (wid * 2 + 1) * 4 + l16;
  const char* vg0 = (const char*)vt_ws + (size_t)bh * 262144 + (size_t)d0v * 4096 +
                    (((lane & 15) ^ (d0v & 15)) << 4);
  const char* vg1 = (const char*)vt_ws + (size_t)bh * 262144 + (size_t)d1v * 4096 +
                    (((lane & 15) ^ (d1v & 15)) << 4);

  f32x16 o0a, o0b, o1a, o1b, lacc;
#pragma unroll
  for (int r = 0; r < 16; r++) {
    o0a[r] = 0.f; o0b[r] = 0.f; o1a[r] = 0.f; o1b[r] = 0.f; lacc[r] = 0.f;
  }

  // prologue: stage tiles 0,1 into bufs 0,1
#pragma unroll
  for (int p = 0; p < 2; p++) {
    glds16(kgl0 + (size_t)p * 16384, smem + p * 16384 + wid * 2048);
    glds16(kgl1 + (size_t)p * 16384, smem + p * 16384 + wid * 2048 + 1024);
    glds16(vg0 + (size_t)p * 256, smem + 65536 + p * 16384 + wid * 2048);
    glds16(vg1 + (size_t)p * 256, smem + 65536 + p * 16384 + wid * 2048 + 1024);
  }
  asm volatile("s_waitcnt vmcnt(0)" ::: "memory");
  __builtin_amdgcn_s_barrier();

  for (int kt = 0; kt < 16; ++kt) {
    const int kb_off = (kt & 3) * 16384;
    const int vb_off = 65536 + (kt & 3) * 16384;
    if (kt + 2 < 16) {  // stage tile kt+2 into buf (kt+2)&3 == (kt-2)&3
      const int nb = ((kt + 2) & 3) * 16384;
      glds16(kgl0 + (size_t)(kt + 2) * 16384, smem + nb + wid * 2048);
      glds16(kgl1 + (size_t)(kt + 2) * 16384, smem + nb + wid * 2048 + 1024);
      glds16(vg0 + (size_t)(kt + 2) * 256, smem + 65536 + nb + wid * 2048);
      glds16(vg1 + (size_t)(kt + 2) * 256, smem + 65536 + nb + wid * 2048 + 1024);
    }

    // ---- S^T = K * Q^T : 4 independent 32-key groups ----
    f32x16 s0, s1, s2, s3;
#pragma unroll
    for (int r = 0; r < 16; r++) { s0[r] = 0.f; s1[r] = 0.f; s2[r] = 0.f; s3[r] = 0.f; }
#pragma unroll
    for (int st = 0; st < 4; st++) {
      const int doff = (st * 32 + hi16) ^ xorv;
      short8 ka = *(const short8*)(smem + kb_off + lq * 128 + doff);
      short8 kb = *(const short8*)(smem + kb_off + (lq + 32) * 128 + doff);
      short8 kc = *(const short8*)(smem + kb_off + (lq + 64) * 128 + doff);
      short8 kd = *(const short8*)(smem + kb_off + (lq + 96) * 128 + doff);
      __builtin_amdgcn_s_setprio(1);
      s0 = __builtin_amdgcn_mfma_f32_32x32x16_bf16(ka, qf[st], s0, 0, 0, 0);
      s1 = __builtin_amdgcn_mfma_f32_32x32x16_bf16(kb, qf[st], s1, 0, 0, 0);
      s2 = __builtin_amdgcn_mfma_f32_32x32x16_bf16(kc, qf[st], s2, 0, 0, 0);
      s3 = __builtin_amdgcn_mfma_f32_32x32x16_bf16(kd, qf[st], s3, 0, 0, 0);
      __builtin_amdgcn_s_setprio(0);
    }

    // ---- no-max softmax (scale pre-folded into Q); deferred row-sum ----
#pragma unroll
    for (int r = 0; r < 16; r++) {
      s0[r] = __builtin_amdgcn_exp2f(s0[r]);
      s1[r] = __builtin_amdgcn_exp2f(s1[r]);
      s2[r] = __builtin_amdgcn_exp2f(s2[r]);
      s3[r] = __builtin_amdgcn_exp2f(s3[r]);
    }
#pragma unroll
    for (int r = 0; r < 16; r++)
      lacc[r] += (s0[r] + s1[r]) + (s2[r] + s3[r]);

    // ---- O^T += V^T * P^T ; pi-perm makes P-frags pure packing ----
#define PV_KB(S, KB, OA, OB)                                                     \
  {                                                                              \
    union { uint u[4]; short8 s8; } ua, ub;                                      \
    ua.u[0] = pk2(S[0], S[1]);   ua.u[1] = pk2(S[2], S[3]);                      \
    ua.u[2] = pk2(S[8], S[9]);   ua.u[3] = pk2(S[10], S[11]);                    \
    ub.u[0] = pk2(S[4], S[5]);   ub.u[1] = pk2(S[6], S[7]);                      \
    ub.u[2] = pk2(S[12], S[13]); ub.u[3] = pk2(S[14], S[15]);                    \
    const int c0 = (((KB) * 4 + hi) ^ (lq & 15)) << 4;                           \
    const int c1 = (((KB) * 4 + 2 + hi) ^ (lq & 15)) << 4;                       \
    short8 va0 = *(const short8*)(smem + vb_off + lq * 256 + c0);                \
    short8 va1 = *(const short8*)(smem + vb_off + (lq + 32) * 256 + c0);         \
    short8 vb0 = *(const short8*)(smem + vb_off + lq * 256 + c1);                \
    short8 vb1 = *(const short8*)(smem + vb_off + (lq + 32) * 256 + c1);         \
    __builtin_amdgcn_s_setprio(1);                                               \
    OA = __builtin_amdgcn_mfma_f32_32x32x16_bf16(va0, ua.s8, OA, 0, 0, 0);       \
    OB = __builtin_amdgcn_mfma_f32_32x32x16_bf16(va1, ua.s8, OB, 0, 0, 0);       \
    OA = __builtin_amdgcn_mfma_f32_32x32x16_bf16(vb0, ub.s8, OA, 0, 0, 0);       \
    OB = __builtin_amdgcn_mfma_f32_32x32x16_bf16(vb1, ub.s8, OB, 0, 0, 0);       \
    __builtin_amdgcn_s_setprio(0);                                               \
  }
    PV_KB(s0, 0, o0a, o1a)
    PV_KB(s1, 1, o0b, o1b)
    PV_KB(s2, 2, o0a, o1a)
    PV_KB(s3, 3, o0b, o1b)
#undef PV_KB

    if ((kt & 1) && kt < 15) {  // pair barrier: after odd iters only
      asm volatile("s_waitcnt vmcnt(0)" ::: "memory");
      __builtin_amdgcn_s_barrier();
    }
  }
  __syncthreads();

  // ---- final row-sum (one tree), 1/l, transpose via rotated LDS ----
  float l;
  {
    float sm[8];
#pragma unroll
    for (int i = 0; i < 8; i++) sm[i] = lacc[i] + lacc[i + 8];
#pragma unroll
    for (int i = 0; i < 4; i++) sm[i] += sm[i + 4];
    l = (sm[0] + sm[1]) + (sm[2] + sm[3]);
    l += __shfl_xor(l, 32);
  }
  f32x16 o0, o1;
#pragma unroll
  for (int r = 0; r < 16; r++) { o0[r] = o0a[r] + o0b[r]; o1[r] = o1a[r] + o1b[r]; }
  float* ep = (float*)(smem) + wid * 1024;
  const float invl = 1.f / l;
  const int eq = lane >> 1, eds = lane & 1;
  float* obase = out + ((size_t)b * 2048 + qb * 256 + wid * 32 + eq) * 1024 +
                 h * 64 + eds * 16;
#pragma unroll
  for (int db = 0; db < 2; db++) {
#pragma unroll
    for (int r = 0; r < 16; r++) {
      int d = (r & 3) + 8 * (r >> 2) + 4 * hi;
      float v = (db ? o1[r] : o0[r]) * invl;
      ep[lq * 32 + ((d + lq) & 31)] = v;
    }
#pragma unroll
    for (int c = 0; c < 4; c++) {
      float4 t;
      t.x = ep[eq * 32 + ((eds * 16 + 4 * c + 0 + eq) & 31)];
      t.y = ep[eq * 32 + ((eds * 16 + 4 * c + 1 + eq) & 31)];
      t.z = ep[eq * 32 + ((eds * 16 + 4 * c + 2 + eq) & 31)];
      t.w = ep[eq * 32 + ((eds * 16 + 4 * c + 3 + eq) & 31)];
      *(float4*)(obase + db * 32 + 4 * c) = t;
    }
  }
}

// ---------------------------------------------------------------- launch
extern "C" void kernel_launch(void* const* d_in, const int* in_sizes, int n_in,
                              void* d_out, int out_size, void* d_ws, size_t ws_size,
                              hipStream_t stream) {
  (void)in_sizes; (void)n_in; (void)out_size; (void)ws_size;
  const float* src  = (const float*)d_in[0];
  const float* w    = (const float*)d_in[1];
  const float* bias = (const float*)d_in[2];
  float* out = (float*)d_out;

  char* ws = (char*)d_ws;
  bf16* src_bf = (bf16*)ws;                             // 8,388,608 B
  bf16* wt_bf  = (bf16*)(ws + 8388608);                 // 6,291,456 B
  bf16* q_ws   = (bf16*)(ws + 8388608 + 6291456);       // 32*2048*64 each
  bf16* k_ws   = q_ws + 4194304;
  bf16* vt_ws  = k_ws + 4194304;

  prep_kernel<<<5632, 256, 0, stream>>>((const float4*)src, src_bf, w, wt_bf);
  qkv_gemm_kernel<<<dim3(32, 24), 256, 0, stream>>>(src_bf, wt_bf, bias, q_ws, k_ws, vt_ws);
  attn9_kernel<<<256, 512, 0, stream>>>(q_ws, k_ws, vt_ws, out);
}